// Round 11
// baseline (199.397 us; speedup 1.0000x reference)
//
#include <hip/hip_runtime.h>
#include <hip/hip_fp16.h>
#include <math.h>

#define BB 4
#define NQ 256
#define NK 1024
#define DD 256
#define HH 256
#define NSEG 4
#define NBLK 1024

typedef __attribute__((ext_vector_type(8))) _Float16 f16x8;
typedef __attribute__((ext_vector_type(4))) _Float16 f16x4;
typedef __attribute__((ext_vector_type(4))) float f32x4;

struct SMem {
    union {
        struct { __half Wt[32][260]; } p;                               // 16.6 KB
        struct { __half sQ[32][264]; __half sK[32][264]; float sW[HH]; } s; // 34.8 KB
        struct { float sPt[2][32][36]; float sV[2][32][36];
                 float sAll[3][64][17]; float sRowsum[32]; } v;         // 31.6 KB
    } u;
};

#define AGENT __HIP_MEMORY_SCOPE_AGENT

// ---------------- proj tile: MFMA-f16, E=exp(2x) fp16 out -------------------
// t in [0,640): mt=t>>3 (64-row tile), nt=t&7 (32-col tile).
__device__ __forceinline__ void dev_proj_tile(
    int t, SMem& sm, int tid,
    const float* __restrict__ Q, const float* __restrict__ K,
    const float* __restrict__ Wq, const float* __restrict__ Wk,
    const int* __restrict__ vlen,
    __half* __restrict__ Eq, __half* __restrict__ Ek, int* projcnt)
{
    int mt = t >> 3, nt = t & 7;
    const float *A, *W; __half* C; int bm;
    bool masked = false;
    if (mt < 16) { A = Q; W = Wq; C = Eq; bm = mt * 64; }
    else {
        int kt = mt - 16;
        int b = kt >> 4;
        int lr = (kt & 15) * 64;
        masked = (lr >= vlen[b]);          // fully masked K-tile: skip compute
        A = K; W = Wk; C = Ek; bm = kt * 64;
    }
    int bn = nt * 32;

    if (!masked) {
        auto& Wt = sm.u.p.Wt;
        {
            int dp = tid >> 3, cg = tid & 7;
#pragma unroll
            for (int pp = 0; pp < 4; ++pp) {
                int d0r = (dp + pp * 32) * 2;
                float4 r0 = *(const float4*)&W[(size_t)d0r * HH + bn + cg * 4];
                float4 r1 = *(const float4*)&W[(size_t)(d0r + 1) * HH + bn + cg * 4];
                int n = cg * 4;
                *(__half2*)&Wt[n + 0][d0r] = __floats2half2_rn(r0.x, r1.x);
                *(__half2*)&Wt[n + 1][d0r] = __floats2half2_rn(r0.y, r1.y);
                *(__half2*)&Wt[n + 2][d0r] = __floats2half2_rn(r0.z, r1.z);
                *(__half2*)&Wt[n + 3][d0r] = __floats2half2_rn(r0.w, r1.w);
            }
        }
        __syncthreads();

        int lane = tid & 63, w = tid >> 6;
        int wm = w & 1, wn = w >> 1;
        int lm = lane & 15, lk = (lane >> 4) * 4;

        const float* arow0 = A + (size_t)(bm + wm * 32 + lm) * DD;
        const float* arow1 = arow0 + (size_t)16 * DD;
        const __half* brow = &Wt[wn * 16 + lm][0];

        f32x4 acc0 = {0.f, 0.f, 0.f, 0.f};
        f32x4 acc1 = {0.f, 0.f, 0.f, 0.f};

        float4 a00 = *(const float4*)(arow0 + lk);
        float4 a01 = *(const float4*)(arow0 + 16 + lk);
        float4 a10 = *(const float4*)(arow1 + lk);
        float4 a11 = *(const float4*)(arow1 + 16 + lk);
        f16x4 b0 = *(const f16x4*)&brow[lk];
        f16x4 b1 = *(const f16x4*)&brow[16 + lk];

#pragma unroll
        for (int s = 0; s < 8; ++s) {
            float4 c00 = a00, c01 = a01, c10 = a10, c11 = a11;
            f16x4 cb0 = b0, cb1 = b1;
            if (s < 7) {
                int d = (s + 1) * 32;
                a00 = *(const float4*)(arow0 + d + lk);
                a01 = *(const float4*)(arow0 + d + 16 + lk);
                a10 = *(const float4*)(arow1 + d + lk);
                a11 = *(const float4*)(arow1 + d + 16 + lk);
                b0 = *(const f16x4*)&brow[d + lk];
                b1 = *(const f16x4*)&brow[d + 16 + lk];
            }
            f16x8 af0, af1, bf;
            af0[0] = (_Float16)c00.x; af0[1] = (_Float16)c00.y;
            af0[2] = (_Float16)c00.z; af0[3] = (_Float16)c00.w;
            af0[4] = (_Float16)c01.x; af0[5] = (_Float16)c01.y;
            af0[6] = (_Float16)c01.z; af0[7] = (_Float16)c01.w;
            af1[0] = (_Float16)c10.x; af1[1] = (_Float16)c10.y;
            af1[2] = (_Float16)c10.z; af1[3] = (_Float16)c10.w;
            af1[4] = (_Float16)c11.x; af1[5] = (_Float16)c11.y;
            af1[6] = (_Float16)c11.z; af1[7] = (_Float16)c11.w;
            bf[0] = cb0[0]; bf[1] = cb0[1]; bf[2] = cb0[2]; bf[3] = cb0[3];
            bf[4] = cb1[0]; bf[5] = cb1[1]; bf[6] = cb1[2]; bf[7] = cb1[3];
            acc0 = __builtin_amdgcn_mfma_f32_16x16x32_f16(af0, bf, acc0, 0, 0, 0);
            acc1 = __builtin_amdgcn_mfma_f32_16x16x32_f16(af1, bf, acc1, 0, 0, 0);
        }

        int mB0 = bm + wm * 32 + (lane >> 4) * 4;
        int mB1 = mB0 + 16;
        int n = bn + wn * 16 + lm;
#pragma unroll
        for (int r = 0; r < 4; ++r) {
            float e0 = __expf(2.f * fminf(fmaxf(acc0[r], -5.5f), 5.5f));
            float e1 = __expf(2.f * fminf(fmaxf(acc1[r], -5.5f), 5.5f));
            C[(size_t)(mB0 + r) * HH + n] = __float2half(e0);
            C[(size_t)(mB1 + r) * HH + n] = __float2half(e1);
        }
    }
    if (projcnt) {                          // fused mode: publish tile
        __syncthreads();                    // all threads' stores drained
        if (tid == 0)
            __hip_atomic_fetch_add(&projcnt[mt], 1, __ATOMIC_RELEASE, AGENT);
    }
}

// ---------------- scores tile: P = exp(-2T) + per-chunk row sums ------------
__device__ __forceinline__ void dev_scores_tile(
    int t, SMem& sm, int tid,
    const __half* __restrict__ Eq, const __half* __restrict__ Ek,
    const float* __restrict__ wv, const int* __restrict__ vlen,
    float* __restrict__ P, float* __restrict__ Psum,
    int* projcnt, int* scnt)
{
    int b = t & 3;
    int rest = t >> 2;
    int qc = rest & 7;
    int kc = rest >> 3;
    int L = vlen[b];
    int k0 = kc * 32;
    if (k0 >= L) return;                    // masked: no signal, not counted
    int q0 = qc * 32;

    if (projcnt) {                          // wait for the 2 producing tiles
        if (tid == 0) {
            int mtq = b * 4 + (qc >> 1);
            int mtk = 16 + b * 16 + (kc >> 1);
            while (__hip_atomic_load(&projcnt[mtq], __ATOMIC_ACQUIRE, AGENT) < 8)
                __builtin_amdgcn_s_sleep(16);
            while (__hip_atomic_load(&projcnt[mtk], __ATOMIC_ACQUIRE, AGENT) < 8)
                __builtin_amdgcn_s_sleep(16);
        }
        __syncthreads();
    }

    auto& sQ = sm.u.s.sQ;
    auto& sK = sm.u.s.sK;
    auto& sW = sm.u.s.sW;
    {
        int c8 = tid & 31;
        int r0 = tid >> 5;
        const __half* gq = Eq + ((size_t)b * NQ + q0) * HH;
        const __half* gk = Ek + ((size_t)b * NK + k0) * HH;
#pragma unroll
        for (int i = 0; i < 4; ++i) {
            int r = r0 + 8 * i;
            *(uint4*)&sQ[r][c8 * 8] = *(const uint4*)&gq[(size_t)r * HH + c8 * 8];
            *(uint4*)&sK[r][c8 * 8] = *(const uint4*)&gk[(size_t)r * HH + c8 * 8];
        }
        sW[tid] = wv[tid];
    }
    __syncthreads();

    int ki = tid & 15, qi = tid >> 4;
    float a00 = 0.f, a01 = 0.f, a10 = 0.f, a11 = 0.f;

#pragma unroll 4
    for (int h4 = 0; h4 < HH / 4; ++h4) {
        float4 w = *(const float4*)&sW[h4 * 4];
        float wxy = w.x + w.y, wzw = w.z + w.w;
        float2 q0a = __half22float2(*(const __half2*)&sQ[qi][h4 * 4]);
        float2 q0b = __half22float2(*(const __half2*)&sQ[qi][h4 * 4 + 2]);
        float2 q1a = __half22float2(*(const __half2*)&sQ[qi + 16][h4 * 4]);
        float2 q1b = __half22float2(*(const __half2*)&sQ[qi + 16][h4 * 4 + 2]);
        float2 k0a = __half22float2(*(const __half2*)&sK[ki][h4 * 4]);
        float2 k0b = __half22float2(*(const __half2*)&sK[ki][h4 * 4 + 2]);
        float2 k1a = __half22float2(*(const __half2*)&sK[ki + 16][h4 * 4]);
        float2 k1b = __half22float2(*(const __half2*)&sK[ki + 16][h4 * 4 + 2]);
        float4 A0 = {q0a.x, q0a.y, q0b.x, q0b.y};
        float4 A1 = {q1a.x, q1a.y, q1b.x, q1b.y};
        float4 B0 = {k0a.x, k0a.y, k0b.x, k0b.y};
        float4 B1 = {k1a.x, k1a.y, k1b.x, k1b.y};
#define QUAD(acc, Aq, Bk)                                                    \
        {                                                                    \
            float E1 = Aq.x * Bk.x, E2 = Aq.y * Bk.y;                        \
            float E3 = Aq.z * Bk.z, E4 = Aq.w * Bk.w;                        \
            float d1 = E1 + 1.f, d2 = E2 + 1.f;                              \
            float d3 = E3 + 1.f, d4 = E4 + 1.f;                              \
            float n12 = fmaf(w.x, E2, fmaf(w.y, E1, wxy));                   \
            float n34 = fmaf(w.z, E4, fmaf(w.w, E3, wzw));                   \
            float d12 = d1 * d2, d34 = d3 * d4;                              \
            float num = fmaf(n12, d34, n34 * d12);                           \
            acc = fmaf(num, __builtin_amdgcn_rcpf(d12 * d34), acc);          \
        }
        QUAD(a00, A0, B0);
        QUAD(a01, A0, B1);
        QUAD(a10, A1, B0);
        QUAD(a11, A1, B1);
#undef QUAD
    }

    int kA = k0 + ki, kB = kA + 16;
    float p00 = (kA < L) ? __expf(-2.f * a00) : 0.f;
    float p10 = (kA < L) ? __expf(-2.f * a10) : 0.f;
    float p01 = (kB < L) ? __expf(-2.f * a01) : 0.f;
    float p11 = (kB < L) ? __expf(-2.f * a11) : 0.f;

    float* s0 = P + ((size_t)b * NQ + q0 + qi) * NK;
    float* s1 = P + ((size_t)b * NQ + q0 + qi + 16) * NK;
    s0[kA] = p00; s0[kB] = p01;
    s1[kA] = p10; s1[kB] = p11;

    float r0s = p00 + p01, r1s = p10 + p11;
#pragma unroll
    for (int o = 1; o <= 8; o <<= 1) {
        r0s += __shfl_xor(r0s, o, 64);
        r1s += __shfl_xor(r1s, o, 64);
    }
    if (ki == 0) {
        Psum[((size_t)b * NQ + q0 + qi) * 32 + kc] = r0s;
        Psum[((size_t)b * NQ + q0 + qi + 16) * 32 + kc] = r1s;
    }

    if (scnt) {
        __syncthreads();
        if (tid == 0)
            __hip_atomic_fetch_add(&scnt[b * 8 + qc], 1, __ATOMIC_RELEASE, AGENT);
    }
}

// ---------------- pv segment + last-seg combine (fused mode) ----------------
__device__ __forceinline__ void dev_pv_seg(
    int t, SMem& sm, int tid,
    const float* __restrict__ P, const float* __restrict__ V,
    const float* __restrict__ Psum, const int* __restrict__ vlen,
    float* __restrict__ Opart, float* __restrict__ out,
    int* scnt, int* segcnt, int* sflag)
{
    int b = t & 3;
    int qt = (t >> 2) & 7, dt = (t >> 5) & 7, seg = t >> 8;
    int q0 = qt * 32, d0 = dt * 32;
    int L = vlen[b];
    int nc = (L + 31) >> 5;

    if (tid == 0) {                         // wait all active scores tiles
        while (__hip_atomic_load(&scnt[b * 8 + qt], __ATOMIC_ACQUIRE, AGENT) < nc)
            __builtin_amdgcn_s_sleep(16);
    }
    __syncthreads();

    int c0 = (nc * seg) / NSEG, c1 = (nc * (seg + 1)) / NSEG;

    auto& sPt = sm.u.v.sPt;
    auto& sV  = sm.u.v.sV;
    auto& sAll = sm.u.v.sAll;

    int r = tid >> 3, c4 = tid & 7;
    int w = tid >> 6, sp = tid & 63;
    int qg = sp >> 3, dg = sp & 7;

    const float* Pb = P + ((size_t)b * NQ + q0 + r) * NK;
    const float* Vb = V + (size_t)b * NK * DD + d0;

    int cld = (c0 < c1) ? c0 : 0;
    float4 pf = *(const float4*)(Pb + cld * 32 + c4 * 4);
    float4 vf = *(const float4*)(Vb + (size_t)(cld * 32 + r) * DD + c4 * 4);

    float acc[4][4] = {};

    for (int c = c0; c < c1; ++c) {
        int cur = c & 1;
        sPt[cur][c4 * 4 + 0][r] = pf.x;
        sPt[cur][c4 * 4 + 1][r] = pf.y;
        sPt[cur][c4 * 4 + 2][r] = pf.z;
        sPt[cur][c4 * 4 + 3][r] = pf.w;
        *(float4*)&sV[cur][r][c4 * 4] = vf;
        if (c + 1 < c1) {
            int kn = (c + 1) * 32;
            pf = *(const float4*)(Pb + kn + c4 * 4);
            vf = *(const float4*)(Vb + (size_t)(kn + r) * DD + c4 * 4);
        }
        __syncthreads();
#pragma unroll
        for (int kk = 0; kk < 8; ++kk) {
            float4 A  = *(const float4*)&sPt[cur][w * 8 + kk][qg * 4];
            float4 Bv = *(const float4*)&sV[cur][w * 8 + kk][dg * 4];
            acc[0][0] = fmaf(A.x, Bv.x, acc[0][0]);
            acc[0][1] = fmaf(A.x, Bv.y, acc[0][1]);
            acc[0][2] = fmaf(A.x, Bv.z, acc[0][2]);
            acc[0][3] = fmaf(A.x, Bv.w, acc[0][3]);
            acc[1][0] = fmaf(A.y, Bv.x, acc[1][0]);
            acc[1][1] = fmaf(A.y, Bv.y, acc[1][1]);
            acc[1][2] = fmaf(A.y, Bv.z, acc[1][2]);
            acc[1][3] = fmaf(A.y, Bv.w, acc[1][3]);
            acc[2][0] = fmaf(A.z, Bv.x, acc[2][0]);
            acc[2][1] = fmaf(A.z, Bv.y, acc[2][1]);
            acc[2][2] = fmaf(A.z, Bv.z, acc[2][2]);
            acc[2][3] = fmaf(A.z, Bv.w, acc[2][3]);
            acc[3][0] = fmaf(A.w, Bv.x, acc[3][0]);
            acc[3][1] = fmaf(A.w, Bv.y, acc[3][1]);
            acc[3][2] = fmaf(A.w, Bv.z, acc[3][2]);
            acc[3][3] = fmaf(A.w, Bv.w, acc[3][3]);
        }
    }

    __syncthreads();                        // sPt/sV done; sAll reuse safe
    if (w > 0) {
#pragma unroll
        for (int i = 0; i < 4; ++i)
#pragma unroll
            for (int j = 0; j < 4; ++j) sAll[w - 1][sp][i * 4 + j] = acc[i][j];
    }
    __syncthreads();
    if (w == 0) {
#pragma unroll
        for (int ww = 0; ww < 3; ++ww)
#pragma unroll
            for (int i = 0; i < 4; ++i)
#pragma unroll
                for (int j = 0; j < 4; ++j) acc[i][j] += sAll[ww][sp][i * 4 + j];
        float* op = Opart + (size_t)seg * (BB * NQ * DD);
#pragma unroll
        for (int i = 0; i < 4; ++i) {
            float4 o = { acc[i][0], acc[i][1], acc[i][2], acc[i][3] };
            *(float4*)&op[((size_t)b * NQ + q0 + qg * 4 + i) * DD + d0 + dg * 4] = o;
        }
    }

    __syncthreads();                        // drain Opart stores (all threads)
    if (tid == 0) {
        int old = __hip_atomic_fetch_add(&segcnt[t & 255], 1,
                                         __ATOMIC_ACQ_REL, AGENT);
        *sflag = old;
    }
    __syncthreads();
    if (*sflag == NSEG - 1) {               // last seg combines + normalizes
        auto& sRowsum = sm.u.v.sRowsum;
        if (tid < 32) {
            float s = 0.f;
            const float* pp = Psum + ((size_t)b * NQ + q0 + tid) * 32;
            for (int c = 0; c < nc; ++c) s += pp[c];
            sRowsum[tid] = s;
        }
        __syncthreads();
        int qi = tid >> 3, cc = tid & 7;
        const size_t SEGSZ = (size_t)BB * NQ * DD;
        size_t off = ((size_t)b * NQ + q0 + qi) * DD + d0 + cc * 4;
        float4 o = {0.f, 0.f, 0.f, 0.f};
#pragma unroll
        for (int s = 0; s < NSEG; ++s) {
            float4 x = *(const float4*)&Opart[s * SEGSZ + off];
            o.x += x.x; o.y += x.y; o.z += x.z; o.w += x.w;
        }
        float inv = 1.0f / sRowsum[qi];
        o.x *= inv; o.y *= inv; o.z *= inv; o.w *= inv;
        *(float4*)&out[off] = o;
    }
}

// ---------------- fused cooperative kernel (no grid.sync) -------------------
__global__ __launch_bounds__(256, 4) void fused_all(
    const float* __restrict__ queries, const float* __restrict__ keys,
    const float* __restrict__ values, const int* __restrict__ vlen,
    const float* __restrict__ Wq, const float* __restrict__ Wk,
    const float* __restrict__ wv, float* __restrict__ out,
    __half* __restrict__ Eqh, __half* __restrict__ Ekh,
    float* __restrict__ P, float* __restrict__ Psum,
    float* __restrict__ Opart, int* __restrict__ flags)
{
    __shared__ SMem sm;
    __shared__ int sflag;
    int tid = threadIdx.x;
    int bid = blockIdx.x;

    int* projcnt = flags;          // [80]
    int* scnt    = flags + 128;    // [32]
    int* segcnt  = flags + 256;    // [256]

    if (bid < 640)
        dev_proj_tile(bid, sm, tid, queries, keys, Wq, Wk, vlen,
                      Eqh, Ekh, projcnt);
    __syncthreads();               // union switch p -> s

    dev_scores_tile(bid, sm, tid, Eqh, Ekh, wv, vlen, P, Psum,
                    projcnt, scnt);
    __syncthreads();               // union switch s -> v

    dev_pv_seg(bid, sm, tid, P, values, Psum, vlen, Opart, out,
               scnt, segcnt, &sflag);
}

// ---------------- standalone fallback kernels (R10 path) --------------------
__global__ __launch_bounds__(256) void proj_sa(
    const float* __restrict__ Q, const float* __restrict__ K,
    const float* __restrict__ Wq, const float* __restrict__ Wk,
    const int* __restrict__ vlen, __half* __restrict__ Eq,
    __half* __restrict__ Ek)
{
    __shared__ SMem sm;
    dev_proj_tile(blockIdx.x, sm, threadIdx.x, Q, K, Wq, Wk, vlen,
                  Eq, Ek, nullptr);
}

__global__ __launch_bounds__(256) void scores_sa(
    const __half* __restrict__ Eq, const __half* __restrict__ Ek,
    const float* __restrict__ wv, const int* __restrict__ vlen,
    float* __restrict__ P, float* __restrict__ Psum)
{
    __shared__ SMem sm;
    dev_scores_tile(blockIdx.x, sm, threadIdx.x, Eq, Ek, wv, vlen, P, Psum,
                    nullptr, nullptr);
}

__global__ __launch_bounds__(256) void pv_sa(
    const float* __restrict__ P, const float* __restrict__ V,
    const float* __restrict__ Psum, const int* __restrict__ vlen,
    float* __restrict__ out)
{
    __shared__ __align__(16) float sPt[2][32][36];
    __shared__ __align__(16) float sV[2][32][36];
    __shared__ float sAll[3][64][17];
    __shared__ float sRowsum[32];

    int bid = blockIdx.x;
    int b = bid & 3;
    int rest = bid >> 2;
    int qt = rest >> 3, dt = rest & 7;
    int q0 = qt * 32, d0 = dt * 32;
    int L = vlen[b];
    int nc = (L + 31) >> 5;

    int tid = threadIdx.x;
    if (tid < 32) {
        float s = 0.f;
        const float* pp = Psum + ((size_t)b * NQ + q0 + tid) * 32;
        for (int c = 0; c < nc; ++c) s += pp[c];
        sRowsum[tid] = s;
    }

    int r = tid >> 3, c4 = tid & 7;
    int w = tid >> 6, sp = tid & 63;
    int qg = sp >> 3, dg = sp & 7;

    const float* Pb = P + ((size_t)b * NQ + q0 + r) * NK;
    const float* Vb = V + (size_t)b * NK * DD + d0;

    float4 pf = *(const float4*)(Pb + c4 * 4);
    float4 vf = *(const float4*)(Vb + (size_t)r * DD + c4 * 4);

    float acc[4][4] = {};

    for (int c = 0; c < nc; ++c) {
        int cur = c & 1;
        sPt[cur][c4 * 4 + 0][r] = pf.x;
        sPt[cur][c4 * 4 + 1][r] = pf.y;
        sPt[cur][c4 * 4 + 2][r] = pf.z;
        sPt[cur][c4 * 4 + 3][r] = pf.w;
        *(float4*)&sV[cur][r][c4 * 4] = vf;
        if (c + 1 < nc) {
            int kn = (c + 1) * 32;
            pf = *(const float4*)(Pb + kn + c4 * 4);
            vf = *(const float4*)(Vb + (size_t)(kn + r) * DD + c4 * 4);
        }
        __syncthreads();
#pragma unroll
        for (int kk = 0; kk < 8; ++kk) {
            float4 A  = *(const float4*)&sPt[cur][w * 8 + kk][qg * 4];
            float4 Bv = *(const float4*)&sV[cur][w * 8 + kk][dg * 4];
            acc[0][0] = fmaf(A.x, Bv.x, acc[0][0]);
            acc[0][1] = fmaf(A.x, Bv.y, acc[0][1]);
            acc[0][2] = fmaf(A.x, Bv.z, acc[0][2]);
            acc[0][3] = fmaf(A.x, Bv.w, acc[0][3]);
            acc[1][0] = fmaf(A.y, Bv.x, acc[1][0]);
            acc[1][1] = fmaf(A.y, Bv.y, acc[1][1]);
            acc[1][2] = fmaf(A.y, Bv.z, acc[1][2]);
            acc[1][3] = fmaf(A.y, Bv.w, acc[1][3]);
            acc[2][0] = fmaf(A.z, Bv.x, acc[2][0]);
            acc[2][1] = fmaf(A.z, Bv.y, acc[2][1]);
            acc[2][2] = fmaf(A.z, Bv.z, acc[2][2]);
            acc[2][3] = fmaf(A.z, Bv.w, acc[2][3]);
            acc[3][0] = fmaf(A.w, Bv.x, acc[3][0]);
            acc[3][1] = fmaf(A.w, Bv.y, acc[3][1]);
            acc[3][2] = fmaf(A.w, Bv.z, acc[3][2]);
            acc[3][3] = fmaf(A.w, Bv.w, acc[3][3]);
        }
    }

    if (w > 0) {
#pragma unroll
        for (int i = 0; i < 4; ++i)
#pragma unroll
            for (int j = 0; j < 4; ++j) sAll[w - 1][sp][i * 4 + j] = acc[i][j];
    }
    __syncthreads();
    if (w == 0) {
#pragma unroll
        for (int ww = 0; ww < 3; ++ww)
#pragma unroll
            for (int i = 0; i < 4; ++i)
#pragma unroll
                for (int j = 0; j < 4; ++j) acc[i][j] += sAll[ww][sp][i * 4 + j];
#pragma unroll
        for (int i = 0; i < 4; ++i) {
            float inv = 1.0f / sRowsum[qg * 4 + i];
            float4 o = { acc[i][0] * inv, acc[i][1] * inv,
                         acc[i][2] * inv, acc[i][3] * inv };
            *(float4*)&out[((size_t)b * NQ + q0 + qg * 4 + i) * DD + d0 + dg * 4] = o;
        }
    }
}

extern "C" void kernel_launch(void* const* d_in, const int* in_sizes, int n_in,
                              void* d_out, int out_size, void* d_ws, size_t ws_size,
                              hipStream_t stream) {
    const float* queries = (const float*)d_in[0];  // [B,NQ,D]
    const float* keys    = (const float*)d_in[1];  // [B,NK,D]
    const float* values  = (const float*)d_in[2];  // [B,NK,D]
    const int*   vlens   = (const int*)d_in[3];    // [B]
    const float* Wq      = (const float*)d_in[4];  // [D,H]
    const float* Wk      = (const float*)d_in[5];  // [D,H]
    const float* wv      = (const float*)d_in[6];  // [H]
    float* out = (float*)d_out;

    int*    flags = (int*)d_ws;                            // 4 KB (zeroed below)
    __half* Eqh   = (__half*)((char*)d_ws + 4096);         // 512 KB
    __half* Ekh   = Eqh + (size_t)BB * NQ * HH;            // 2 MB
    float*  P     = (float*)(Ekh + (size_t)BB * NK * HH);  // 4 MB
    float*  Psum  = P + (size_t)BB * NQ * NK;              // 128 KB
    float*  Opart = Psum + (size_t)BB * NQ * 32;           // 4 MB (4 segs)

    // Flags must be zero at every call (ws is NOT re-poisoned between replays).
    hipMemsetAsync(flags, 0, 4096, stream);

    void* args[] = { (void*)&queries, (void*)&keys, (void*)&values,
                     (void*)&vlens, (void*)&Wq, (void*)&Wk, (void*)&wv,
                     (void*)&out, (void*)&Eqh, (void*)&Ekh, (void*)&P,
                     (void*)&Psum, (void*)&Opart, (void*)&flags };
    hipError_t e = hipLaunchCooperativeKernel((void*)fused_all,
                                              dim3(NBLK), dim3(256),
                                              args, 0, stream);
    if (e != hipSuccess) {
        // Fallback: proven 3-kernel path (R10).
        proj_sa<<<dim3(640), 256, 0, stream>>>(queries, keys, Wq, Wk, vlens,
                                               Eqh, Ekh);
        scores_sa<<<dim3(BB * (NQ / 32) * (NK / 32)), 256, 0, stream>>>(
            Eqh, Ekh, wv, vlens, P, Psum);
        pv_sa<<<dim3(BB * (NQ / 32) * (DD / 32)), 256, 0, stream>>>(
            P, values, Psum, vlens, out);
    }
}

// Round 12
// 52.602 us; speedup vs baseline: 3.7907x; 3.7907x over previous
//
#include <hip/hip_runtime.h>
#include <hip/hip_fp16.h>
#include <math.h>

#define BB 4
#define NQ 256
#define NK 1024
#define DD 256
#define HH 256

typedef __attribute__((ext_vector_type(8))) _Float16 f16x8;
typedef __attribute__((ext_vector_type(4))) _Float16 f16x4;
typedef __attribute__((ext_vector_type(4))) float f32x4;

// ---------------- K1: MFMA-f16 projection + E=exp(2x) epilogue --------------
// (byte-identical to R10, known-good)
// E[m,h] = exp(2*clamp(proj, -5.5, 5.5)) as fp16 (e^11 = 59874 < 65504).
// tanh(z) = 1 - 2/(1+e^{2z}) applied implicitly downstream.
__global__ __launch_bounds__(256) void proj_mfma_kernel(
    const float* __restrict__ Q, const float* __restrict__ K,
    const float* __restrict__ Wq, const float* __restrict__ Wk,
    const int* __restrict__ vlen,
    __half* __restrict__ Eq, __half* __restrict__ Ek)
{
    int bx = blockIdx.x;
    int mt = bx >> 3, nt = bx & 7;
    const float *A, *W; __half* C; int bm;
    if (mt < 16) { A = Q; W = Wq; C = Eq; bm = mt * 64; }
    else {
        int kt = mt - 16;                 // 0..63
        int b = kt >> 4;
        int lr = (kt & 15) * 64;          // batch-local row start
        if (lr >= vlen[b]) return;        // fully masked K-tile: skip
        A = K; W = Wk; C = Ek; bm = kt * 64;
    }
    int bn = nt * 32;

    __shared__ __half Wt[32][260];        // [n][d] transposed W tile, fp16

    int tid = threadIdx.x;
    {   // one-time W^T stage
        int dp = tid >> 3, cg = tid & 7;
#pragma unroll
        for (int pp = 0; pp < 4; ++pp) {
            int d0r = (dp + pp * 32) * 2;
            float4 r0 = *(const float4*)&W[(size_t)d0r * HH + bn + cg * 4];
            float4 r1 = *(const float4*)&W[(size_t)(d0r + 1) * HH + bn + cg * 4];
            int n = cg * 4;
            *(__half2*)&Wt[n + 0][d0r] = __floats2half2_rn(r0.x, r1.x);
            *(__half2*)&Wt[n + 1][d0r] = __floats2half2_rn(r0.y, r1.y);
            *(__half2*)&Wt[n + 2][d0r] = __floats2half2_rn(r0.z, r1.z);
            *(__half2*)&Wt[n + 3][d0r] = __floats2half2_rn(r0.w, r1.w);
        }
    }
    __syncthreads();

    int lane = tid & 63, w = tid >> 6;
    int wm = w & 1, wn = w >> 1;
    int lm = lane & 15, lk = (lane >> 4) * 4;

    const float* arow0 = A + (size_t)(bm + wm * 32 + lm) * DD;
    const float* arow1 = arow0 + (size_t)16 * DD;
    const __half* brow = &Wt[wn * 16 + lm][0];

    f32x4 acc0 = {0.f, 0.f, 0.f, 0.f};
    f32x4 acc1 = {0.f, 0.f, 0.f, 0.f};

    float4 a00 = *(const float4*)(arow0 + lk);
    float4 a01 = *(const float4*)(arow0 + 16 + lk);
    float4 a10 = *(const float4*)(arow1 + lk);
    float4 a11 = *(const float4*)(arow1 + 16 + lk);
    f16x4 b0 = *(const f16x4*)&brow[lk];
    f16x4 b1 = *(const f16x4*)&brow[16 + lk];

#pragma unroll
    for (int s = 0; s < 8; ++s) {
        float4 c00 = a00, c01 = a01, c10 = a10, c11 = a11;
        f16x4 cb0 = b0, cb1 = b1;
        if (s < 7) {
            int d = (s + 1) * 32;
            a00 = *(const float4*)(arow0 + d + lk);
            a01 = *(const float4*)(arow0 + d + 16 + lk);
            a10 = *(const float4*)(arow1 + d + lk);
            a11 = *(const float4*)(arow1 + d + 16 + lk);
            b0 = *(const f16x4*)&brow[d + lk];
            b1 = *(const f16x4*)&brow[d + 16 + lk];
        }
        f16x8 af0, af1, bf;
        af0[0] = (_Float16)c00.x; af0[1] = (_Float16)c00.y;
        af0[2] = (_Float16)c00.z; af0[3] = (_Float16)c00.w;
        af0[4] = (_Float16)c01.x; af0[5] = (_Float16)c01.y;
        af0[6] = (_Float16)c01.z; af0[7] = (_Float16)c01.w;
        af1[0] = (_Float16)c10.x; af1[1] = (_Float16)c10.y;
        af1[2] = (_Float16)c10.z; af1[3] = (_Float16)c10.w;
        af1[4] = (_Float16)c11.x; af1[5] = (_Float16)c11.y;
        af1[6] = (_Float16)c11.z; af1[7] = (_Float16)c11.w;
        bf[0] = cb0[0]; bf[1] = cb0[1]; bf[2] = cb0[2]; bf[3] = cb0[3];
        bf[4] = cb1[0]; bf[5] = cb1[1]; bf[6] = cb1[2]; bf[7] = cb1[3];
        acc0 = __builtin_amdgcn_mfma_f32_16x16x32_f16(af0, bf, acc0, 0, 0, 0);
        acc1 = __builtin_amdgcn_mfma_f32_16x16x32_f16(af1, bf, acc1, 0, 0, 0);
    }

    // D layout (m89): n = lane&15, m = (lane>>4)*4 + reg
    int mB0 = bm + wm * 32 + (lane >> 4) * 4;
    int mB1 = mB0 + 16;
    int n = bn + wn * 16 + lm;
#pragma unroll
    for (int r = 0; r < 4; ++r) {
        float e0 = __expf(2.f * fminf(fmaxf(acc0[r], -5.5f), 5.5f));
        float e1 = __expf(2.f * fminf(fmaxf(acc1[r], -5.5f), 5.5f));
        C[(size_t)(mB0 + r) * HH + n] = __float2half(e0);
        C[(size_t)(mB1 + r) * HH + n] = __float2half(e1);
    }
}

// ---------------- K2: scores -> P = exp(-2T) + per-chunk row sums -----------
// T(q,k) = sum_h w_h/(1+Eq_h*Ek_h); logit = -2T. PAIR-rational:
// w1/d1 + w2/d2 = (w1*d2 + w2*d1)/(d1*d2), d = fma(Eq,Ek,1).
// 12 VALU + 2 rcp per 4 h-terms (was 17+1). den <= e^44, safe in f32.
__global__ __launch_bounds__(256) void scores_kernel(
    const __half* __restrict__ Eq, const __half* __restrict__ Ek,
    const float* __restrict__ wv, const int* __restrict__ vlen,
    float* __restrict__ P, float* __restrict__ Psum)
{
    __shared__ __align__(16) __half sQ[32][HH + 8];
    __shared__ __align__(16) __half sK[32][HH + 8];
    __shared__ __align__(16) float sW[HH];

    int bid = blockIdx.x;
    int b = bid & 3;
    int rest = bid >> 2;
    int qc = rest & 7;
    int kc = rest >> 3;
    int L = vlen[b];
    int k0 = kc * 32;
    if (k0 >= L) return;             // fully masked chunk: uniform exit
    int q0 = qc * 32;

    int tid = threadIdx.x;
    {
        int c8 = tid & 31;
        int r0 = tid >> 5;
        const __half* gq = Eq + ((size_t)b * NQ + q0) * HH;
        const __half* gk = Ek + ((size_t)b * NK + k0) * HH;
#pragma unroll
        for (int i = 0; i < 4; ++i) {
            int r = r0 + 8 * i;
            *(uint4*)&sQ[r][c8 * 8] = *(const uint4*)&gq[(size_t)r * HH + c8 * 8];
            *(uint4*)&sK[r][c8 * 8] = *(const uint4*)&gk[(size_t)r * HH + c8 * 8];
        }
        sW[tid] = wv[tid];
    }
    __syncthreads();

    int ki = tid & 15, qi = tid >> 4;
    float a00 = 0.f, a01 = 0.f, a10 = 0.f, a11 = 0.f;

#pragma unroll 4
    for (int h4 = 0; h4 < HH / 4; ++h4) {
        float4 w = *(const float4*)&sW[h4 * 4];
        float2 q0a = __half22float2(*(const __half2*)&sQ[qi][h4 * 4]);
        float2 q0b = __half22float2(*(const __half2*)&sQ[qi][h4 * 4 + 2]);
        float2 q1a = __half22float2(*(const __half2*)&sQ[qi + 16][h4 * 4]);
        float2 q1b = __half22float2(*(const __half2*)&sQ[qi + 16][h4 * 4 + 2]);
        float2 k0a = __half22float2(*(const __half2*)&sK[ki][h4 * 4]);
        float2 k0b = __half22float2(*(const __half2*)&sK[ki][h4 * 4 + 2]);
        float2 k1a = __half22float2(*(const __half2*)&sK[ki + 16][h4 * 4]);
        float2 k1b = __half22float2(*(const __half2*)&sK[ki + 16][h4 * 4 + 2]);
        float4 A0 = {q0a.x, q0a.y, q0b.x, q0b.y};
        float4 A1 = {q1a.x, q1a.y, q1b.x, q1b.y};
        float4 B0 = {k0a.x, k0a.y, k0b.x, k0b.y};
        float4 B1 = {k1a.x, k1a.y, k1b.x, k1b.y};
#define PAIR4(acc, Aq, Bk)                                                   \
        {                                                                    \
            float d1 = fmaf(Aq.x, Bk.x, 1.f);                                \
            float d2 = fmaf(Aq.y, Bk.y, 1.f);                                \
            float n12 = fmaf(w.y, d1, w.x * d2);                             \
            acc = fmaf(n12, __builtin_amdgcn_rcpf(d1 * d2), acc);            \
            float d3 = fmaf(Aq.z, Bk.z, 1.f);                                \
            float d4 = fmaf(Aq.w, Bk.w, 1.f);                                \
            float n34 = fmaf(w.w, d3, w.z * d4);                             \
            acc = fmaf(n34, __builtin_amdgcn_rcpf(d3 * d4), acc);            \
        }
        PAIR4(a00, A0, B0);
        PAIR4(a01, A0, B1);
        PAIR4(a10, A1, B0);
        PAIR4(a11, A1, B1);
#undef PAIR4
    }

    int kA = k0 + ki, kB = kA + 16;
    float p00 = (kA < L) ? __expf(-2.f * a00) : 0.f;
    float p10 = (kA < L) ? __expf(-2.f * a10) : 0.f;
    float p01 = (kB < L) ? __expf(-2.f * a01) : 0.f;
    float p11 = (kB < L) ? __expf(-2.f * a11) : 0.f;

    float* s0 = P + ((size_t)b * NQ + q0 + qi) * NK;
    float* s1 = P + ((size_t)b * NQ + q0 + qi + 16) * NK;
    s0[kA] = p00; s0[kB] = p01;
    s1[kA] = p10; s1[kB] = p11;

    float r0s = p00 + p01, r1s = p10 + p11;
#pragma unroll
    for (int o = 1; o <= 8; o <<= 1) {
        r0s += __shfl_xor(r0s, o, 64);
        r1s += __shfl_xor(r1s, o, 64);
    }
    if (ki == 0) {
        Psum[((size_t)b * NQ + q0 + qi) * 32 + kc] = r0s;
        Psum[((size_t)b * NQ + q0 + qi + 16) * 32 + kc] = r1s;
    }
}

// ---------------- K3: PV GEMM + normalize, 512 blocks (2/CU) ----------------
// 16q x 32d per block, 2x4 micro, 4-way k-split across waves, register-staged
// double buffering. Role-split staging: tid<128 stages P, tid>=128 stages V.
__global__ __launch_bounds__(256) void pv_kernel(
    const float* __restrict__ P, const float* __restrict__ V,
    const float* __restrict__ Psum, const int* __restrict__ vlen,
    float* __restrict__ out)
{
    __shared__ __align__(16) float sPt[2][32][18];   // [k][q], 2-way alias free
    __shared__ __align__(16) float sV[2][32][36];    // [k][d]
    __shared__ float sAll[3][64][9];
    __shared__ float sRowsum[16];

    int bid = blockIdx.x;
    int b = bid & 3;
    int rest = bid >> 2;
    int qt = rest >> 3, dt = rest & 7;   // qt 0..15, dt 0..7
    int q0 = qt * 16, d0 = dt * 32;
    int L = vlen[b];
    int nc = (L + 31) >> 5;

    int tid = threadIdx.x;
    if (tid < 16) {
        float s = 0.f;
        const float* pp = Psum + ((size_t)b * NQ + q0 + tid) * 32;
        for (int c = 0; c < nc; ++c) s += pp[c];
        sRowsum[tid] = s;
    }

    // staging roles
    bool isP = tid < 128;
    int pr = tid >> 3, pc4 = tid & 7;            // P: row 0..15, f4 col 0..7
    int vt = tid & 127;
    int vr = vt >> 2, vc = (vt & 3) * 2;         // V: row 0..31, f4 cols vc,vc+1

    // compute roles
    int w = tid >> 6, sp = tid & 63;
    int qg = sp >> 3, dg = sp & 7;               // qg 0..7 (2 rows), dg 0..7

    const float* Pb = P + ((size_t)b * NQ + q0 + pr) * NK;
    const float* Vb = V + (size_t)b * NK * DD + d0;

    float4 pf = {0,0,0,0}, vfa = {0,0,0,0}, vfb = {0,0,0,0};
    if (isP) pf = *(const float4*)(Pb + pc4 * 4);
    else {
        vfa = *(const float4*)(Vb + (size_t)vr * DD + vc * 4);
        vfb = *(const float4*)(Vb + (size_t)vr * DD + vc * 4 + 4);
    }

    float acc[2][4] = {};

    for (int c = 0; c < nc; ++c) {
        int cur = c & 1;
        if (isP) {
            sPt[cur][pc4 * 4 + 0][pr] = pf.x;
            sPt[cur][pc4 * 4 + 1][pr] = pf.y;
            sPt[cur][pc4 * 4 + 2][pr] = pf.z;
            sPt[cur][pc4 * 4 + 3][pr] = pf.w;
        } else {
            *(float4*)&sV[cur][vr][vc * 4] = vfa;
            *(float4*)&sV[cur][vr][vc * 4 + 4] = vfb;
        }
        if (c + 1 < nc) {
            int kn = (c + 1) * 32;
            if (isP) pf = *(const float4*)(Pb + kn + pc4 * 4);
            else {
                vfa = *(const float4*)(Vb + (size_t)(kn + vr) * DD + vc * 4);
                vfb = *(const float4*)(Vb + (size_t)(kn + vr) * DD + vc * 4 + 4);
            }
        }
        __syncthreads();
#pragma unroll
        for (int kk = 0; kk < 8; ++kk) {
            float2 A  = *(const float2*)&sPt[cur][w * 8 + kk][qg * 2];
            float4 Bv = *(const float4*)&sV[cur][w * 8 + kk][dg * 4];
            acc[0][0] = fmaf(A.x, Bv.x, acc[0][0]);
            acc[0][1] = fmaf(A.x, Bv.y, acc[0][1]);
            acc[0][2] = fmaf(A.x, Bv.z, acc[0][2]);
            acc[0][3] = fmaf(A.x, Bv.w, acc[0][3]);
            acc[1][0] = fmaf(A.y, Bv.x, acc[1][0]);
            acc[1][1] = fmaf(A.y, Bv.y, acc[1][1]);
            acc[1][2] = fmaf(A.y, Bv.z, acc[1][2]);
            acc[1][3] = fmaf(A.y, Bv.w, acc[1][3]);
        }
        // single barrier per chunk (double-buffered)
    }

    if (w > 0) {
#pragma unroll
        for (int i = 0; i < 2; ++i)
#pragma unroll
            for (int j = 0; j < 4; ++j) sAll[w - 1][sp][i * 4 + j] = acc[i][j];
    }
    __syncthreads();
    if (w == 0) {
#pragma unroll
        for (int ww = 0; ww < 3; ++ww)
#pragma unroll
            for (int i = 0; i < 2; ++i)
#pragma unroll
                for (int j = 0; j < 4; ++j) acc[i][j] += sAll[ww][sp][i * 4 + j];
#pragma unroll
        for (int i = 0; i < 2; ++i) {
            float inv = 1.0f / sRowsum[qg * 2 + i];
            float4 o = { acc[i][0] * inv, acc[i][1] * inv,
                         acc[i][2] * inv, acc[i][3] * inv };
            *(float4*)&out[((size_t)b * NQ + q0 + qg * 2 + i) * DD + d0 + dg * 4] = o;
        }
    }
}

extern "C" void kernel_launch(void* const* d_in, const int* in_sizes, int n_in,
                              void* d_out, int out_size, void* d_ws, size_t ws_size,
                              hipStream_t stream) {
    const float* queries = (const float*)d_in[0];  // [B,NQ,D]
    const float* keys    = (const float*)d_in[1];  // [B,NK,D]
    const float* values  = (const float*)d_in[2];  // [B,NK,D]
    const int*   vlens   = (const int*)d_in[3];    // [B]
    const float* Wq      = (const float*)d_in[4];  // [D,H]
    const float* Wk      = (const float*)d_in[5];  // [D,H]
    const float* wv      = (const float*)d_in[6];  // [H]
    float* out = (float*)d_out;

    __half* Eqh = (__half*)d_ws;                         // 512 KB
    __half* Ekh = Eqh + (size_t)BB * NQ * HH;            // 2 MB
    float*  P    = (float*)(Ekh + (size_t)BB * NK * HH); // 4 MB
    float*  Psum = P + (size_t)BB * NQ * NK;             // 128 KB

    proj_mfma_kernel<<<dim3(640), 256, 0, stream>>>(
        queries, keys, Wq, Wk, vlens, Eqh, Ekh);

    scores_kernel<<<dim3(BB * (NQ / 32) * (NK / 32)), 256, 0, stream>>>(
        Eqh, Ekh, wv, vlens, P, Psum);

    pv_kernel<<<dim3(BB * (NQ / 16) * (DD / 32)), 256, 0, stream>>>(
        P, values, Psum, vlens, out);
}